// Round 11
// baseline (4011.785 us; speedup 1.0000x reference)
//
#include <hip/hip_runtime.h>

// SpikeMLP — R22: forced v_pk_fma_f32 (inline asm) + free operand pairing.
// Chain contract (FROZEN, verified absmax=0.0 @ R14-R16,R18-R21):
//   per C element: acc = fma(a_k, w_k, acc), k = 0..1023 strictly
//   ascending, single accumulator, fp32, contract off. v_pk_fma_f32 =
//   two INDEPENDENT IEEE fmas; pairing across adjacent n-columns only.
// R21 post-mortem: VALUBusy(78%) x 1600us = 1250us VALU issue = scalar
//   FMA floor (874) + overhead => __builtin_elementwise_fma did NOT form
//   pk; kernel family is ISSUE-bound (also explains R14==R15 per-FLOP
//   issue parity). R22 forces pk via asm and makes pairing free:
//   - n-pairing: w-pairs are sub-registers of float4 LDS reads (free)
//   - A DUPLICATED in LDS (As2[kk][2m]=[2m+1]=a): {a,a} pairs read as
//     sub-registers of broadcast float4 reads (no per-kk v_movs)
//   Per kk: 32 pk + 6 ds_read = 38 issue slots vs ~68 scalar.
// Predicted: LDS 49152 (3 blk/CU), VGPR ~96-128, WRITE 262MB, big GEMM
//   ~1000-1200us, total ~2.6-3.0ms, absmax 0.0. Flat => DS-bound, next
//   round rebalances DS (undo A-dup, m-pairing).

typedef float f2 __attribute__((ext_vector_type(2)));

static constexpr int BSZ   = 4096;
static constexpr int D_IN  = 1024;
static constexpr int H1    = 1024;
static constexpr int D_OUT = 512;
static constexpr int M_ROWS = BSZ * 16;   // 65536, m = b*16 + t

// ---------------------------------------------------------------------------
// pack X [B, D_in, T=16] f32 -> A [m = b*16 + t][d] f32 (spikes exactly 0/1)
// ---------------------------------------------------------------------------
__global__ void pack_x(const float* __restrict__ X, float* __restrict__ A) {
    const int P = blockIdx.x * 256 + threadIdx.x;     // P = b*1024 + d
    const int b = P >> 10, d = P & 1023;
    const float4* xp = (const float4*)(X + (size_t)P * 16);
    float4 x0 = xp[0], x1 = xp[1], x2 = xp[2], x3 = xp[3];
    const float v[16] = {x0.x, x0.y, x0.z, x0.w, x1.x, x1.y, x1.z, x1.w,
                         x2.x, x2.y, x2.z, x2.w, x3.x, x3.y, x3.z, x3.w};
#pragma unroll
    for (int t = 0; t < 16; ++t)
        A[((size_t)(b * 16 + t)) * 1024 + d] = v[t];
}

// ---------------------------------------------------------------------------
// GEMM, reference fp32 chain. C[m][n] = A[m,:] . W[n,:], K = 1024.
// Block 128(M) x 128(N), 256 threads, 8x8 per thread. BK = 32.
// LDS: As2 k-major with each a DUPLICATED ([kk][2m],[2m+1]); Ws k-major.
// Inner loop: v_pk_fma_f32 over n-pairs, operands as free sub-reg pairs.
// Single ascending accumulator over full K (frozen chain).
// ---------------------------------------------------------------------------
__global__ __launch_bounds__(256, 2) void gemm_np(
    const float* __restrict__ A,    // [M, 1024] f32 spikes (exactly 0/1)
    const float* __restrict__ W,    // [N, 1024] f32 weights (raw input)
    float* __restrict__ C,          // [M, N] fp32
    int N) {
#pragma clang fp contract(off)
    __shared__ float As2[32][256];  // [kk][2m] duplicated  32 KB
    __shared__ float Ws[32][128];   // [kk][n]              16 KB

    const int tid = threadIdx.x;
    const int tx = tid & 15;        // n quads: tx*4 and 64+tx*4
    const int ty = tid >> 4;        // m group: rows ty*8 .. ty*8+7
    const int m0 = blockIdx.x * 128, n0 = blockIdx.y * 128;

    const int arow = tid & 127, akh = tid >> 7;   // staging: row, k-half

    const float* Ab = A + (size_t)(m0 + arow) * 1024 + akh * 16;
    const float* Wb = W + (size_t)(n0 + arow) * 1024 + akh * 16;

    f2 acc2[8][4] = {};   // single-chain accumulators, paired over n

    for (int kt = 0; kt < 32; ++kt) {
        const int k0 = kt * 32;
        // global reads (issue before barrier)
        float4 av0 = *(const float4*)(Ab + k0);
        float4 av1 = *(const float4*)(Ab + k0 + 4);
        float4 av2 = *(const float4*)(Ab + k0 + 8);
        float4 av3 = *(const float4*)(Ab + k0 + 12);
        float4 wv0 = *(const float4*)(Wb + k0);
        float4 wv1 = *(const float4*)(Wb + k0 + 4);
        float4 wv2 = *(const float4*)(Wb + k0 + 8);
        float4 wv3 = *(const float4*)(Wb + k0 + 12);
        __syncthreads();             // previous tile fully consumed
        {
            const float avv[16] = {av0.x, av0.y, av0.z, av0.w,
                                   av1.x, av1.y, av1.z, av1.w,
                                   av2.x, av2.y, av2.z, av2.w,
                                   av3.x, av3.y, av3.z, av3.w};
            const float wvv[16] = {wv0.x, wv0.y, wv0.z, wv0.w,
                                   wv1.x, wv1.y, wv1.z, wv1.w,
                                   wv2.x, wv2.y, wv2.z, wv2.w,
                                   wv3.x, wv3.y, wv3.z, wv3.w};
#pragma unroll
            for (int c = 0; c < 16; ++c) {
                // duplicated A write: one ds_write_b64 of {v,v}
                *(f2*)&As2[akh * 16 + c][2 * arow] = (f2){avv[c], avv[c]};
                Ws[akh * 16 + c][arow] = wvv[c];
            }
        }
        __syncthreads();

#pragma unroll
        for (int kk = 0; kk < 32; ++kk) {         // strictly k-ascending
            // A pairs {a,a}: sub-registers of broadcast float4 reads
            float4 ad0 = *(const float4*)&As2[kk][16 * ty];
            float4 ad1 = *(const float4*)&As2[kk][16 * ty + 4];
            float4 ad2 = *(const float4*)&As2[kk][16 * ty + 8];
            float4 ad3 = *(const float4*)&As2[kk][16 * ty + 12];
            float4 w0  = *(const float4*)&Ws[kk][tx * 4];
            float4 w1  = *(const float4*)&Ws[kk][64 + tx * 4];
            const f2 ap[8] = {{ad0.x, ad0.y}, {ad0.z, ad0.w},
                              {ad1.x, ad1.y}, {ad1.z, ad1.w},
                              {ad2.x, ad2.y}, {ad2.z, ad2.w},
                              {ad3.x, ad3.y}, {ad3.z, ad3.w}};
            const f2 wp[4] = {{w0.x, w0.y}, {w0.z, w0.w},
                              {w1.x, w1.y}, {w1.z, w1.w}};
#pragma unroll
            for (int i = 0; i < 8; ++i)
#pragma unroll
                for (int jp = 0; jp < 4; ++jp)
                    asm("v_pk_fma_f32 %0, %1, %2, %0"
                        : "+v"(acc2[i][jp])
                        : "v"(ap[i]), "v"(wp[jp]));
        }
    }

#pragma unroll
    for (int i = 0; i < 8; ++i) {
        float4 s0 = {acc2[i][0][0], acc2[i][0][1], acc2[i][1][0], acc2[i][1][1]};
        float4 s1 = {acc2[i][2][0], acc2[i][2][1], acc2[i][3][0], acc2[i][3][1]};
        const size_t r = (size_t)(m0 + ty * 8 + i) * N;
        *(float4*)&C[r + n0 + tx * 4]      = s0;
        *(float4*)&C[r + n0 + 64 + tx * 4] = s1;
    }
}

// ---------------------------------------------------------------------------
// fp32 LIF recurrence, numpy ufunc order, contraction off (frozen).
// In-place: Z holds GEMM output, overwritten with f32 spikes (exact 0/1).
// ---------------------------------------------------------------------------
__global__ void recur_hidden(float* __restrict__ Z, const float* __restrict__ bias) {
#pragma clang fp contract(off)
    const int idx = blockIdx.x * 256 + threadIdx.x;   // b*1024 + n
    const int n = idx & 1023, b = idx >> 10;
    const float bb = bias[n];
    float c = 0.f, v = 0.f, s = 0.f;
#pragma unroll
    for (int t = 0; t < 16; ++t) {
        const size_t p = (size_t)(b * 16 + t) * 1024 + n;
        const float z = Z[p];
        const float t1 = c * 0.5f;
        const float t2 = t1 + z;
        c = t2 + bb;
        const float u1 = v * 0.75f;
        const float u2 = u1 * (1.0f - s);
        v = u2 + c;
        s = (v > 0.5f) ? 1.0f : 0.0f;
        Z[p] = s;                                     // exact 0/1 f32
    }
}

__global__ void recur_out(const float* __restrict__ Z, const float* __restrict__ bias,
                          float* __restrict__ Out) {
#pragma clang fp contract(off)
    const int idx = blockIdx.x * 256 + threadIdx.x;   // b*512 + n
    const int n = idx & 511, b = idx >> 9;
    const float bb = bias[n];
    float c = 0.f, v = 0.f, s = 0.f, acm = 0.f;
#pragma unroll
    for (int t = 0; t < 16; ++t) {
        const float z = Z[(size_t)(b * 16 + t) * 512 + n];
        const float t1 = c * 0.5f;
        const float t2 = t1 + z;
        c = t2 + bb;
        const float u1 = v * 0.75f;
        const float u2 = u1 * (1.0f - s);
        v = u2 + c;
        s = (v > 0.5f) ? 1.0f : 0.0f;
        acm += s;                                     // small ints, exact
    }
    Out[(size_t)b * 512 + n] = acm * 0.0625f;         // exact (2^-4)
}

// ---------------------------------------------------------------------------
extern "C" void kernel_launch(void* const* d_in, const int* in_sizes, int n_in,
                              void* d_out, int out_size, void* d_ws, size_t ws_size,
                              hipStream_t stream) {
    const float* X  = (const float*)d_in[0];
    const float* W1 = (const float*)d_in[1];
    const float* b1 = (const float*)d_in[2];
    const float* W2 = (const float*)d_in[3];
    const float* b2 = (const float*)d_in[4];
    const float* Wo = (const float*)d_in[5];
    const float* bo = (const float*)d_in[6];

    char* ws = (char*)d_ws;
    float* buf0 = (float*)ws;                      // 256 MiB (A1 / Z2=S2)
    float* buf1 = (float*)(ws + (256ull << 20));   // 256 MiB (Z1=S1 / Z3)

    pack_x<<<(BSZ * D_IN) / 256, 256, 0, stream>>>(X, buf0);

    // layer 1: A=buf0 -> Z=buf1, spikes in-place in buf1
    gemm_np<<<dim3(M_ROWS / 128, H1 / 128), 256, 0, stream>>>(buf0, W1, buf1, H1);
    recur_hidden<<<(BSZ * H1) / 256, 256, 0, stream>>>(buf1, b1);
    // layer 2: A=buf1 -> Z=buf0 (overwrites A1, no longer needed)
    gemm_np<<<dim3(M_ROWS / 128, H1 / 128), 256, 0, stream>>>(buf1, W2, buf0, H1);
    recur_hidden<<<(BSZ * H1) / 256, 256, 0, stream>>>(buf0, b2);
    // output layer: A=buf0 -> Z=buf1 [M,512]
    gemm_np<<<dim3(M_ROWS / 128, D_OUT / 128), 256, 0, stream>>>(buf0, Wo, buf1, D_OUT);
    recur_out<<<(BSZ * D_OUT) / 256, 256, 0, stream>>>(buf1, bo, (float*)d_out);
}

// Round 12
// 3918.351 us; speedup vs baseline: 1.0238x; 1.0238x over previous
//
#include <hip/hip_runtime.h>

// SpikeMLP — R23: R21 scalar structure + register-prefetch pipeline
// (single 32KB LDS buffer, latency hidden under compute).
// Chain contract (FROZEN, verified absmax=0.0 @ R14-R16,R18-R22):
//   per C element: acc = fma(a_k, w_k, acc), k = 0..1023 strictly
//   ascending, single accumulator, fp32, contract off. Recurrence fp32
//   ufunc order. MFMA / k-reassociation forbidden.
// Evidence ledger (big-GEMM dur):
//   R14 8x4: 1758 | R15/R20 8x8: 1713 | R21 +f32 acts: ~1600 (BEST)
//   R16 LDS-dbuf@2blk: 1810 | R22 pk_fma: 1740 -> v_pk_fma_f32 is
//   HALF-RATE on gfx950 (VALU-busy TIME identical to scalar) — packed
//   fp32 is a no-op lever. Scalar v_fma_f32 it is, forever.
// R23 theory: R20/R21 issue tile-kt loads at top of iter kt; vmcnt(0)
//   lands right after barrier-1 => ~300cyc exposed latency per tile per
//   wave (the m97-style barrier drain). Fix WITHOUT losing occupancy:
//   prefetch kt+1 into REGISTERS before compute of kt; write to LDS
//   after next barrier. Same 32KB LDS, same 2 barriers, +32 VGPR.
// Predicted: VGPR ~100-128, WRITE 262MB (no spill!), VALUBusy ~85%,
//   big GEMM ~1350-1480us, total ~3.4-3.6ms, absmax 0.0.
//   Flat => latency already hidden; next = global_load_lds layout or
//   accept ceiling.

static constexpr int BSZ   = 4096;
static constexpr int D_IN  = 1024;
static constexpr int H1    = 1024;
static constexpr int D_OUT = 512;
static constexpr int M_ROWS = BSZ * 16;   // 65536, m = b*16 + t

// ---------------------------------------------------------------------------
// pack X [B, D_in, T=16] f32 -> A [m = b*16 + t][d] f32 (spikes exactly 0/1)
// ---------------------------------------------------------------------------
__global__ void pack_x(const float* __restrict__ X, float* __restrict__ A) {
    const int P = blockIdx.x * 256 + threadIdx.x;     // P = b*1024 + d
    const int b = P >> 10, d = P & 1023;
    const float4* xp = (const float4*)(X + (size_t)P * 16);
    float4 x0 = xp[0], x1 = xp[1], x2 = xp[2], x3 = xp[3];
    const float v[16] = {x0.x, x0.y, x0.z, x0.w, x1.x, x1.y, x1.z, x1.w,
                         x2.x, x2.y, x2.z, x2.w, x3.x, x3.y, x3.z, x3.w};
#pragma unroll
    for (int t = 0; t < 16; ++t)
        A[((size_t)(b * 16 + t)) * 1024 + d] = v[t];
}

// ---------------------------------------------------------------------------
// GEMM, reference fp32 chain. C[m][n] = A[m,:] . W[n,:], K = 1024.
// Block 128(M) x 128(N), 256 threads, 8x8 per thread. BK = 32, k-major LDS,
// single buffer; REGISTER prefetch one tile ahead (loads issued before the
// compute that hides them). Two barriers per tile.
// Thread (tx,ty): rows ty*8..+7, cols {tx*4..+3, 64+tx*4..+3}.
// ---------------------------------------------------------------------------
__global__ __launch_bounds__(256, 2) void gemm_np(
    const float* __restrict__ A,    // [M, 1024] f32 spikes (exactly 0/1)
    const float* __restrict__ W,    // [N, 1024] f32 weights (raw input)
    float* __restrict__ C,          // [M, N] fp32
    int N) {
#pragma clang fp contract(off)
    __shared__ float As[32][128];   // [kk][m]  16 KB
    __shared__ float Ws[32][128];   // [kk][n]  16 KB

    const int tid = threadIdx.x;
    const int tx = tid & 15;        // n quads: tx*4 and 64+tx*4
    const int ty = tid >> 4;        // m group: rows ty*8 .. ty*8+7
    const int m0 = blockIdx.x * 128, n0 = blockIdx.y * 128;

    const int arow = tid & 127, akh = tid >> 7;   // staging: row, k-half

    const float* Ab = A + (size_t)(m0 + arow) * 1024 + akh * 16;
    const float* Wb = W + (size_t)(n0 + arow) * 1024 + akh * 16;

    float pacc[8][8] = {};   // single-chain accumulators

    // prologue: prefetch tile 0 into registers
    float4 pa0 = *(const float4*)(Ab);
    float4 pa1 = *(const float4*)(Ab + 4);
    float4 pa2 = *(const float4*)(Ab + 8);
    float4 pa3 = *(const float4*)(Ab + 12);
    float4 pw0 = *(const float4*)(Wb);
    float4 pw1 = *(const float4*)(Wb + 4);
    float4 pw2 = *(const float4*)(Wb + 8);
    float4 pw3 = *(const float4*)(Wb + 12);

    for (int kt = 0; kt < 32; ++kt) {
        __syncthreads();             // previous tile fully consumed
        // write prefetched tile kt to LDS
        {
            const float avv[16] = {pa0.x, pa0.y, pa0.z, pa0.w,
                                   pa1.x, pa1.y, pa1.z, pa1.w,
                                   pa2.x, pa2.y, pa2.z, pa2.w,
                                   pa3.x, pa3.y, pa3.z, pa3.w};
            const float wvv[16] = {pw0.x, pw0.y, pw0.z, pw0.w,
                                   pw1.x, pw1.y, pw1.z, pw1.w,
                                   pw2.x, pw2.y, pw2.z, pw2.w,
                                   pw3.x, pw3.y, pw3.z, pw3.w};
#pragma unroll
            for (int c = 0; c < 16; ++c) {
                As[akh * 16 + c][arow] = avv[c];   // coalesced b32, 2-way ok
                Ws[akh * 16 + c][arow] = wvv[c];
            }
        }
        // issue tile kt+1 loads — latency hidden under the compute below
        const int ktn = (kt < 31) ? kt + 1 : 31;   // clamped redundant last
        const int k0n = ktn * 32;
        pa0 = *(const float4*)(Ab + k0n);
        pa1 = *(const float4*)(Ab + k0n + 4);
        pa2 = *(const float4*)(Ab + k0n + 8);
        pa3 = *(const float4*)(Ab + k0n + 12);
        pw0 = *(const float4*)(Wb + k0n);
        pw1 = *(const float4*)(Wb + k0n + 4);
        pw2 = *(const float4*)(Wb + k0n + 8);
        pw3 = *(const float4*)(Wb + k0n + 12);
        __syncthreads();             // writes visible

        // compute tile kt (strictly k-ascending, frozen chain)
#pragma unroll
        for (int kk = 0; kk < 32; ++kk) {
            float4 a0 = *(const float4*)&As[kk][ty * 8];
            float4 a1 = *(const float4*)&As[kk][ty * 8 + 4];
            float4 w0 = *(const float4*)&Ws[kk][tx * 4];
            float4 w1 = *(const float4*)&Ws[kk][64 + tx * 4];
            const float a[8] = {a0.x, a0.y, a0.z, a0.w, a1.x, a1.y, a1.z, a1.w};
            const float w[8] = {w0.x, w0.y, w0.z, w0.w, w1.x, w1.y, w1.z, w1.w};
#pragma unroll
            for (int i = 0; i < 8; ++i)
#pragma unroll
                for (int j = 0; j < 8; ++j)
                    pacc[i][j] = __builtin_fmaf(a[i], w[j], pacc[i][j]);
        }
    }

#pragma unroll
    for (int i = 0; i < 8; ++i) {
        float4 s0 = {pacc[i][0], pacc[i][1], pacc[i][2], pacc[i][3]};
        float4 s1 = {pacc[i][4], pacc[i][5], pacc[i][6], pacc[i][7]};
        const size_t r = (size_t)(m0 + ty * 8 + i) * N;
        *(float4*)&C[r + n0 + tx * 4]      = s0;
        *(float4*)&C[r + n0 + 64 + tx * 4] = s1;
    }
}

// ---------------------------------------------------------------------------
// fp32 LIF recurrence, numpy ufunc order, contraction off (frozen).
// In-place: Z holds GEMM output, overwritten with f32 spikes (exact 0/1).
// ---------------------------------------------------------------------------
__global__ void recur_hidden(float* __restrict__ Z, const float* __restrict__ bias) {
#pragma clang fp contract(off)
    const int idx = blockIdx.x * 256 + threadIdx.x;   // b*1024 + n
    const int n = idx & 1023, b = idx >> 10;
    const float bb = bias[n];
    float c = 0.f, v = 0.f, s = 0.f;
#pragma unroll
    for (int t = 0; t < 16; ++t) {
        const size_t p = (size_t)(b * 16 + t) * 1024 + n;
        const float z = Z[p];
        const float t1 = c * 0.5f;
        const float t2 = t1 + z;
        c = t2 + bb;
        const float u1 = v * 0.75f;
        const float u2 = u1 * (1.0f - s);
        v = u2 + c;
        s = (v > 0.5f) ? 1.0f : 0.0f;
        Z[p] = s;                                     // exact 0/1 f32
    }
}

__global__ void recur_out(const float* __restrict__ Z, const float* __restrict__ bias,
                          float* __restrict__ Out) {
#pragma clang fp contract(off)
    const int idx = blockIdx.x * 256 + threadIdx.x;   // b*512 + n
    const int n = idx & 511, b = idx >> 9;
    const float bb = bias[n];
    float c = 0.f, v = 0.f, s = 0.f, acm = 0.f;
#pragma unroll
    for (int t = 0; t < 16; ++t) {
        const float z = Z[(size_t)(b * 16 + t) * 512 + n];
        const float t1 = c * 0.5f;
        const float t2 = t1 + z;
        c = t2 + bb;
        const float u1 = v * 0.75f;
        const float u2 = u1 * (1.0f - s);
        v = u2 + c;
        s = (v > 0.5f) ? 1.0f : 0.0f;
        acm += s;                                     // small ints, exact
    }
    Out[(size_t)b * 512 + n] = acm * 0.0625f;         // exact (2^-4)
}

// ---------------------------------------------------------------------------
extern "C" void kernel_launch(void* const* d_in, const int* in_sizes, int n_in,
                              void* d_out, int out_size, void* d_ws, size_t ws_size,
                              hipStream_t stream) {
    const float* X  = (const float*)d_in[0];
    const float* W1 = (const float*)d_in[1];
    const float* b1 = (const float*)d_in[2];
    const float* W2 = (const float*)d_in[3];
    const float* b2 = (const float*)d_in[4];
    const float* Wo = (const float*)d_in[5];
    const float* bo = (const float*)d_in[6];

    char* ws = (char*)d_ws;
    float* buf0 = (float*)ws;                      // 256 MiB (A1 / Z2=S2)
    float* buf1 = (float*)(ws + (256ull << 20));   // 256 MiB (Z1=S1 / Z3)

    pack_x<<<(BSZ * D_IN) / 256, 256, 0, stream>>>(X, buf0);

    // layer 1: A=buf0 -> Z=buf1, spikes in-place in buf1
    gemm_np<<<dim3(M_ROWS / 128, H1 / 128), 256, 0, stream>>>(buf0, W1, buf1, H1);
    recur_hidden<<<(BSZ * H1) / 256, 256, 0, stream>>>(buf1, b1);
    // layer 2: A=buf1 -> Z=buf0 (overwrites A1, no longer needed)
    gemm_np<<<dim3(M_ROWS / 128, H1 / 128), 256, 0, stream>>>(buf1, W2, buf0, H1);
    recur_hidden<<<(BSZ * H1) / 256, 256, 0, stream>>>(buf0, b2);
    // output layer: A=buf0 -> Z=buf1 [M,512]
    gemm_np<<<dim3(M_ROWS / 128, D_OUT / 128), 256, 0, stream>>>(buf0, Wo, buf1, D_OUT);
    recur_out<<<(BSZ * D_OUT) / 256, 256, 0, stream>>>(buf1, bo, (float*)d_out);
}